// Round 12
// baseline (86.118 us; speedup 1.0000x reference)
//
#include <hip/hip_runtime.h>

#define NND 50000
#define NED 500000
#define F0 64
#define F1 128
#define NCLS 4
#define NG 8
#define PAD 8           // counter padding: 8 uints = 32B/node (2 nodes per 64B line)

#define NBLK 256
#define NTHR 1024
#define EPT 2           // NBLK*NTHR*EPT = 524288 >= NED
#define TAILB 64        // blocks that run G'/I'
#define NBAR 4
#define NSUB 8
#define STG 2048        // per-block hit staging (= NTHR*EPT worst case)
#define STGN 2048
#define BMW ((NND + 31) / 32)
#define EMASK 0x7FFFFu  // e < 2^19

// capacities (expected: n2~80, e3~80, e2~800, n1~800)
#define N1CAP 4096
#define N2CAP 1024
#define E2CAP 8192
#define E3CAP 2048

// cnts: [0]=n1 [1]=n2 [3]=e2 [4]=e3

// write-through store: lands at the coherence point; safe because no XCD
// normal-reads a line before its FINAL write (audited per buffer).
template <typename T>
__device__ __forceinline__ void st_wt(T* p, T v) {
    __hip_atomic_store(p, v, __ATOMIC_RELAXED, __HIP_MEMORY_SCOPE_AGENT);
}

__device__ __forceinline__ bool bt(const unsigned* __restrict__ bm, int n) {
    return (bm[n >> 5] >> (n & 31)) & 1u;
}
// set bit; returns true if this call claimed it
__device__ __forceinline__ bool bclaim(unsigned* bm, int n) {
    unsigned old = atomicOr(&bm[n >> 5], 1u << (n & 31));
    return !(old >> (n & 31) & 1u);
}

__device__ __forceinline__ void load_targets(const int* __restrict__ tnode,
                                             const unsigned* __restrict__ bnn,
                                             int* t) {
    bool is64 = true;
    #pragma unroll
    for (int k = 0; k < 4; k++) if (bnn[2 * k + 1] != 0u) { is64 = false; break; }
    long long off = 0;
    #pragma unroll
    for (int g = 0; g < NG; g++) {
        t[g] = tnode[g] + (int)off;
        off += is64 ? (long long)bnn[2 * g] : (long long)(int)bnn[g];
    }
}

__device__ __forceinline__ int tgt_of(int d, const int* t) {
    int g = -1;
    #pragma unroll
    for (int k = 0; k < NG; k++) if (d == t[k]) g = k;
    return g;
}

// Fence-free grid barrier (R7-R11-proven): write-through data + vmcnt drain
// before s_barrier; two-level arrival; relaxed-load poll.
__device__ __forceinline__ void arrive(unsigned* bar, int i) {
    unsigned* sp = bar + (size_t)(i * (NSUB + 1) + (blockIdx.x & (NSUB - 1))) * 32;
    unsigned* mp = bar + (size_t)(i * (NSUB + 1) + NSUB) * 32;
    unsigned old = __hip_atomic_fetch_add(sp, 1u, __ATOMIC_RELAXED,
                                          __HIP_MEMORY_SCOPE_AGENT);
    if (old + 1u == (unsigned)(NBLK / NSUB))
        __hip_atomic_fetch_add(mp, 1u, __ATOMIC_RELAXED, __HIP_MEMORY_SCOPE_AGENT);
}
__device__ __forceinline__ void waitfull(unsigned* bar, int i) {
    unsigned* mp = bar + (size_t)(i * (NSUB + 1) + NSUB) * 32;
    while (__hip_atomic_load(mp, __ATOMIC_RELAXED, __HIP_MEMORY_SCOPE_AGENT)
           < (unsigned)NSUB)
        __builtin_amdgcn_s_sleep(1);
}
__device__ __forceinline__ void gbar(unsigned* bar, int i) {
    asm volatile("s_waitcnt vmcnt(0)" ::: "memory");
    __syncthreads();
    if (threadIdx.x == 0) { arrive(bar, i); waitfull(bar, i); }
    __syncthreads();
}
// mini-barrier among TAILB blocks (single counter)
__device__ __forceinline__ void gbar_tail(unsigned* bar, int i) {
    asm volatile("s_waitcnt vmcnt(0)" ::: "memory");
    __syncthreads();
    if (threadIdx.x == 0) {
        unsigned* mp = bar + (size_t)(i * (NSUB + 1) + NSUB) * 32;
        __hip_atomic_fetch_add(mp, 1u, __ATOMIC_RELAXED, __HIP_MEMORY_SCOPE_AGENT);
        while (__hip_atomic_load(mp, __ATOMIC_RELAXED, __HIP_MEMORY_SCOPE_AGENT)
               < (unsigned)TAILB)
            __builtin_amdgcn_s_sleep(1);
    }
    __syncthreads();
}

// init: zero cnts/bar/bitmaps/padded-counters/agg buffers (~4.8 MB)
__global__ __launch_bounds__(256) void k_init(char* ws, unsigned zw) {
    unsigned t = blockIdx.x * blockDim.x + threadIdx.x;
    if (t < zw) ((uint4*)ws)[t] = make_uint4(0u, 0u, 0u, 0u);
}

__global__ __launch_bounds__(NTHR) void k_main(
        const float* __restrict__ feat, const float* __restrict__ ew,
        const int* __restrict__ src, const int* __restrict__ dst,
        const int* __restrict__ tnode, const unsigned* __restrict__ bnn,
        const float* __restrict__ W1, const float* __restrict__ b1,
        const float* __restrict__ W2, const float* __restrict__ b2,
        const float* __restrict__ W3, const float* __restrict__ b3,
        float* out,
        int* idx1, int* idx2,
        unsigned* list2, unsigned* list3,
        unsigned* cnts, unsigned* incntP, unsigned* outcntP,
        unsigned* bm1, unsigned* bm2,
        float* agg1c, float* agg2c, unsigned* bar) {
    __shared__ unsigned s_le, s_ln, s_eb, s_nb;
    __shared__ unsigned stage[STG];
    __shared__ int stageN[STGN];

    const int tid = threadIdx.x;
    const int gid = blockIdx.x * NTHR + tid;
    const int lane = tid & 63;
    int tg[NG]; load_targets(tnode, bnn, tg);

    // ---- stage A: unconditional padded degree counting; edges->targets -> list3;
    //      claim node2 ----
    {
        if (tid == 0) { s_le = 0; s_ln = 0; }
        __syncthreads();
        int base = gid * EPT;
        if (base < NED) {
            int2 d2 = *(const int2*)(dst + base);
            int2 s2 = *(const int2*)(src + base);
            int dd[2] = {d2.x, d2.y};
            int ss[2] = {s2.x, s2.y};
            #pragma unroll
            for (int k = 0; k < 2; k++) {
                int d = dd[k], s = ss[k];
                atomicAdd(&incntP[(size_t)d * PAD], 1u);   // true in-degree
                atomicAdd(&outcntP[(size_t)s * PAD], 1u);  // true out-degree
                int g = tgt_of(d, tg);
                if (g >= 0) {
                    int e = base + k;
                    stage[atomicAdd(&s_le, 1u)] = ((unsigned)g << 19) | (unsigned)e;
                    if (bclaim(bm2, s)) stageN[atomicAdd(&s_ln, 1u)] = s;
                }
            }
        }
        __syncthreads();
        if (tid == 0) {
            s_eb = s_le ? atomicAdd(&cnts[4], s_le) : 0u;
            s_nb = s_ln ? atomicAdd(&cnts[1], s_ln) : 0u;
        }
        __syncthreads();
        for (unsigned t = tid; t < s_le; t += NTHR) {
            unsigned p = s_eb + t; if (p < E3CAP) st_wt(&list3[p], stage[t]);
        }
        for (unsigned t = tid; t < s_ln; t += NTHR) {
            int s = stageN[t]; unsigned id = s_nb + t;
            st_wt(&idx2[s], id < N2CAP ? (int)id : -1);
        }
        if (blockIdx.x == 0 && tid < NG * NCLS) st_wt(&out[tid], b3[tid & 3]);
    }
    gbar(bar, 0);

    // ---- stage B: edges into node2 -> list2; claim node1 ----
    {
        if (tid == 0) { s_le = 0; s_ln = 0; }
        __syncthreads();
        int base = gid * EPT;
        if (base < NED) {
            int2 d2 = *(const int2*)(dst + base);
            int dd[2] = {d2.x, d2.y};
            #pragma unroll
            for (int k = 0; k < 2; k++) {
                int d = dd[k];
                if (bt(bm2, d)) {
                    int iv = idx2[d];
                    if ((unsigned)iv < N2CAP) {
                        int e = base + k;
                        stage[atomicAdd(&s_le, 1u)] = ((unsigned)iv << 19) | (unsigned)e;
                        int s = src[e];
                        if (bclaim(bm1, s)) stageN[atomicAdd(&s_ln, 1u)] = s;
                    }
                }
            }
        }
        __syncthreads();
        if (tid == 0) {
            s_eb = s_le ? atomicAdd(&cnts[3], s_le) : 0u;
            s_nb = s_ln ? atomicAdd(&cnts[0], s_ln) : 0u;
        }
        __syncthreads();
        for (unsigned t = tid; t < s_le; t += NTHR) {
            unsigned p = s_eb + t; if (p < E2CAP) st_wt(&list2[p], stage[t]);
        }
        for (unsigned t = tid; t < s_ln; t += NTHR) {
            int s = stageN[t]; unsigned id = s_nb + t;
            st_wt(&idx1[s], id < N1CAP ? (int)id : -1);
        }
    }
    gbar(bar, 1);

    // ---- stage C+E: find edges into node1 AND aggregate them (block-local) ----
    {
        if (tid == 0) s_le = 0;
        __syncthreads();
        int base = gid * EPT;
        if (base < NED) {
            int2 d2 = *(const int2*)(dst + base);
            int dd[2] = {d2.x, d2.y};
            #pragma unroll
            for (int k = 0; k < 2; k++) {
                int d = dd[k];
                if (bt(bm1, d)) {
                    int iv = idx1[d];
                    if ((unsigned)iv < N1CAP)
                        stage[atomicAdd(&s_le, 1u)] =
                            ((unsigned)iv << 19) | (unsigned)(base + k);
                }
            }
        }
        __syncthreads();
        // block-local wave-parallel agg1 over this block's hits
        unsigned cnt = s_le;
        for (unsigned i = (unsigned)(tid >> 6); i < cnt; i += NTHR >> 6) {
            unsigned pk = stage[i];
            int e = pk & EMASK; unsigned i1 = pk >> 19;
            int s = src[e];
            float wt = ew[e] * rsqrtf(fmaxf((float)outcntP[(size_t)s * PAD], 1.f));
            atomicAdd(&agg1c[(size_t)i1 * F0 + lane],
                      feat[(size_t)s * F0 + lane] * wt);
        }
    }
    // barrier 2: all arrive; only tail blocks continue
    {
        asm volatile("s_waitcnt vmcnt(0)" ::: "memory");
        __syncthreads();
        bool tail = blockIdx.x < TAILB;
        if (threadIdx.x == 0) {
            arrive(bar, 2);
            if (tail) waitfull(bar, 2);
        }
        if (!tail) return;
        __syncthreads();
    }

    // ---- stage G' (TAILB blocks): agg2 with h1 computed on the fly ----
    {
        unsigned e2 = cnts[3]; if (e2 > E2CAP) e2 = E2CAP;
        unsigned w = (unsigned)gid >> 6;
        const unsigned nw = (TAILB * NTHR) >> 6;
        for (unsigned i = w; i < e2; i += nw) {
            unsigned pk = list2[i];
            int e = pk & EMASK, i2 = pk >> 19;
            float we = ew[e]; int s = src[e];
            unsigned i1 = (unsigned)idx1[s]; if (i1 >= N1CAP) continue;
            float wt = we * rsqrtf(fmaxf((float)outcntP[(size_t)s * PAD], 1.f));
            float innorm1 = rsqrtf(fmaxf((float)incntP[(size_t)s * PAD], 1.f));
            float rv = agg1c[(size_t)i1 * F0 + lane];
            float acc0 = 0.f, acc1 = 0.f;
            #pragma unroll 8
            for (int k2 = 0; k2 < F0; k2++) {
                float bv = __shfl(rv, k2, 64);
                acc0 += bv * W1[k2 * F1 + lane];
                acc1 += bv * W1[k2 * F1 + lane + 64];
            }
            float h0 = fmaxf(acc0 * innorm1 + b1[lane], 0.f) * wt;
            float h1v = fmaxf(acc1 * innorm1 + b1[lane + 64], 0.f) * wt;
            atomicAdd(&agg2c[(size_t)i2 * F1 + lane], h0);
            atomicAdd(&agg2c[(size_t)i2 * F1 + lane + 64], h1v);
        }
    }
    gbar_tail(bar, 3);

    // ---- stage I' (TAILB blocks): out += (h2-on-the-fly . W3) per e3-edge ----
    {
        unsigned e3 = cnts[4]; if (e3 > E3CAP) e3 = E3CAP;
        unsigned w = (unsigned)gid >> 6;
        const unsigned nw = (TAILB * NTHR) >> 6;
        for (unsigned i = w; i < e3; i += nw) {
            unsigned pk = list3[i];
            int e = pk & EMASK, g = pk >> 19;
            float we = ew[e]; int s = src[e];
            unsigned i2 = (unsigned)idx2[s]; if (i2 >= N2CAP) continue;
            float wt = we * rsqrtf(fmaxf((float)outcntP[(size_t)s * PAD], 1.f))
                          * rsqrtf(fmaxf((float)incntP[(size_t)tg[g] * PAD], 1.f));
            float innorm2 = rsqrtf(fmaxf((float)incntP[(size_t)s * PAD], 1.f));
            float rv0 = agg2c[(size_t)i2 * F1 + lane];
            float rv1 = agg2c[(size_t)i2 * F1 + lane + 64];
            float acc0 = 0.f, acc1 = 0.f;
            #pragma unroll 8
            for (int k2 = 0; k2 < 64; k2++) {
                float bv = __shfl(rv0, k2, 64);
                acc0 += bv * W2[k2 * F1 + lane];
                acc1 += bv * W2[k2 * F1 + lane + 64];
            }
            #pragma unroll 8
            for (int k2 = 0; k2 < 64; k2++) {
                float bv = __shfl(rv1, k2, 64);
                acc0 += bv * W2[(k2 + 64) * F1 + lane];
                acc1 += bv * W2[(k2 + 64) * F1 + lane + 64];
            }
            float h20 = fmaxf(acc0 * innorm2 + b2[lane], 0.f);
            float h21 = fmaxf(acc1 * innorm2 + b2[lane + 64], 0.f);
            float oc0 = (h20 * W3[lane * NCLS + 0] + h21 * W3[(lane + 64) * NCLS + 0]) * wt;
            float oc1 = (h20 * W3[lane * NCLS + 1] + h21 * W3[(lane + 64) * NCLS + 1]) * wt;
            float oc2 = (h20 * W3[lane * NCLS + 2] + h21 * W3[(lane + 64) * NCLS + 2]) * wt;
            float oc3 = (h20 * W3[lane * NCLS + 3] + h21 * W3[(lane + 64) * NCLS + 3]) * wt;
            #pragma unroll
            for (int off = 32; off; off >>= 1) {
                oc0 += __shfl_down(oc0, off, 64);
                oc1 += __shfl_down(oc1, off, 64);
                oc2 += __shfl_down(oc2, off, 64);
                oc3 += __shfl_down(oc3, off, 64);
            }
            if (lane == 0) {
                atomicAdd(&out[g * NCLS + 0], oc0);
                atomicAdd(&out[g * NCLS + 1], oc1);
                atomicAdd(&out[g * NCLS + 2], oc2);
                atomicAdd(&out[g * NCLS + 3], oc3);
            }
        }
    }
}

extern "C" void kernel_launch(void* const* d_in, const int* in_sizes, int n_in,
                              void* d_out, int out_size, void* d_ws, size_t ws_size,
                              hipStream_t stream) {
    const float* in_feat = (const float*)d_in[0];
    const float* ew      = (const float*)d_in[1];
    const int*   src     = (const int*)d_in[2];
    const int*   dst     = (const int*)d_in[3];
    const unsigned* bnn  = (const unsigned*)d_in[4];
    const int*   tnode   = (const int*)d_in[5];
    const float* W1 = (const float*)d_in[6];
    const float* b1 = (const float*)d_in[7];
    const float* W2 = (const float*)d_in[8];
    const float* b2 = (const float*)d_in[9];
    const float* W3 = (const float*)d_in[10];
    const float* b3 = (const float*)d_in[11];
    float* out = (float*)d_out;
    (void)in_sizes; (void)n_in; (void)out_size; (void)ws_size;

    char* ws = (char*)d_ws;
    size_t o = 0;
    auto alloc = [&](size_t bytes) { size_t r = o; o += (bytes + 255) & ~(size_t)255; return r; };

    // --- region zeroed by k_init ---
    size_t off_cnts  = alloc(8 * 4);
    size_t off_bar   = alloc((size_t)NBAR * (NSUB + 1) * 32 * 4);
    size_t off_bm1   = alloc((size_t)BMW * 4);
    size_t off_bm2   = alloc((size_t)BMW * 4);
    size_t off_inc   = alloc((size_t)NND * PAD * 4);
    size_t off_outc  = alloc((size_t)NND * PAD * 4);
    size_t off_agg1  = alloc((size_t)N1CAP * F0 * 4);
    size_t off_agg2  = alloc((size_t)N2CAP * F1 * 4);
    size_t init_bytes = o;
    // --- write-before-read region ---
    size_t off_idx2  = alloc((size_t)NND * 4);
    size_t off_idx1  = alloc((size_t)NND * 4);
    size_t off_list3 = alloc((size_t)E3CAP * 4);
    size_t off_list2 = alloc((size_t)E2CAP * 4);

    unsigned* cnts    = (unsigned*)(ws + off_cnts);
    unsigned* bar     = (unsigned*)(ws + off_bar);
    unsigned* bm1     = (unsigned*)(ws + off_bm1);
    unsigned* bm2     = (unsigned*)(ws + off_bm2);
    unsigned* incntP  = (unsigned*)(ws + off_inc);
    unsigned* outcntP = (unsigned*)(ws + off_outc);
    float*    agg1c   = (float*)(ws + off_agg1);
    float*    agg2c   = (float*)(ws + off_agg2);
    int*      idx2    = (int*)(ws + off_idx2);
    int*      idx1    = (int*)(ws + off_idx1);
    unsigned* list3   = (unsigned*)(ws + off_list3);
    unsigned* list2   = (unsigned*)(ws + off_list2);

    unsigned zw = (unsigned)(init_bytes / 16);
    k_init<<<(int)((zw + 255) / 256), 256, 0, stream>>>(ws, zw);

    k_main<<<NBLK, NTHR, 0, stream>>>(in_feat, ew, src, dst, tnode, bnn,
                                      W1, b1, W2, b2, W3, b3, out,
                                      idx1, idx2, list2, list3,
                                      cnts, incntP, outcntP, bm1, bm2,
                                      agg1c, agg2c, bar);
}

// Round 13
// 67.162 us; speedup vs baseline: 1.2822x; 1.2822x over previous
//
#include <hip/hip_runtime.h>

#define NND 50000
#define NED 500000
#define F0 64
#define F1 128
#define NCLS 4
#define NG 8

#define NBLK 256
#define NTHR 1024
#define EPT 2           // NBLK*NTHR*EPT = 524288 >= NED
#define TAILB 128       // blocks that run E/G'/I'
#define NBAR 6
#define NSUB 8
#define STG 2048        // per-block hit staging (= NTHR*EPT worst case)
#define STGN 2048
#define BMW ((NND + 31) / 32)
#define EMASK 0x7FFFFu  // e < 2^19

// capacities (expected: n2~80, e3~80, e2~800, n1~800, e1~8000)
#define N1CAP 4096
#define N2CAP 1024
#define E1CAP 32768
#define E2CAP 8192
#define E3CAP 2048

// cnts: [0]=n1 [1]=n2 [2]=e1 [3]=e2 [4]=e3  (final by end of stage C)

// write-through store: lands at the coherence point; safe because no XCD
// normal-reads a line before its FINAL write (audited per buffer).
template <typename T>
__device__ __forceinline__ void st_wt(T* p, T v) {
    __hip_atomic_store(p, v, __ATOMIC_RELAXED, __HIP_MEMORY_SCOPE_AGENT);
}

__device__ __forceinline__ bool bt(const unsigned* __restrict__ bm, int n) {
    return (bm[n >> 5] >> (n & 31)) & 1u;
}
// set bit; returns true if this call claimed it
__device__ __forceinline__ bool bclaim(unsigned* bm, int n) {
    unsigned old = atomicOr(&bm[n >> 5], 1u << (n & 31));
    return !(old >> (n & 31) & 1u);
}
__device__ __forceinline__ void bset(unsigned* bm, int n) {
    atomicOr(&bm[n >> 5], 1u << (n & 31));
}

__device__ __forceinline__ void load_targets(const int* __restrict__ tnode,
                                             const unsigned* __restrict__ bnn,
                                             int* t) {
    bool is64 = true;
    #pragma unroll
    for (int k = 0; k < 4; k++) if (bnn[2 * k + 1] != 0u) { is64 = false; break; }
    long long off = 0;
    #pragma unroll
    for (int g = 0; g < NG; g++) {
        t[g] = tnode[g] + (int)off;
        off += is64 ? (long long)bnn[2 * g] : (long long)(int)bnn[g];
    }
}

__device__ __forceinline__ int tgt_of(int d, const int* t) {
    int g = -1;
    #pragma unroll
    for (int k = 0; k < NG; k++) if (d == t[k]) g = k;
    return g;
}

// Fence-free grid barrier (R7-R12-proven): write-through data + vmcnt drain
// before s_barrier; two-level arrival; relaxed-load poll.
__device__ __forceinline__ void arrive(unsigned* bar, int i) {
    unsigned* sp = bar + (size_t)(i * (NSUB + 1) + (blockIdx.x & (NSUB - 1))) * 32;
    unsigned* mp = bar + (size_t)(i * (NSUB + 1) + NSUB) * 32;
    unsigned old = __hip_atomic_fetch_add(sp, 1u, __ATOMIC_RELAXED,
                                          __HIP_MEMORY_SCOPE_AGENT);
    if (old + 1u == (unsigned)(NBLK / NSUB))
        __hip_atomic_fetch_add(mp, 1u, __ATOMIC_RELAXED, __HIP_MEMORY_SCOPE_AGENT);
}
__device__ __forceinline__ void waitfull(unsigned* bar, int i) {
    unsigned* mp = bar + (size_t)(i * (NSUB + 1) + NSUB) * 32;
    while (__hip_atomic_load(mp, __ATOMIC_RELAXED, __HIP_MEMORY_SCOPE_AGENT)
           < (unsigned)NSUB)
        __builtin_amdgcn_s_sleep(1);
}
__device__ __forceinline__ void gbar(unsigned* bar, int i) {
    asm volatile("s_waitcnt vmcnt(0)" ::: "memory");
    __syncthreads();
    if (threadIdx.x == 0) { arrive(bar, i); waitfull(bar, i); }
    __syncthreads();
}
// mini-barrier among TAILB blocks (single counter)
__device__ __forceinline__ void gbar_tail(unsigned* bar, int i) {
    asm volatile("s_waitcnt vmcnt(0)" ::: "memory");
    __syncthreads();
    if (threadIdx.x == 0) {
        unsigned* mp = bar + (size_t)(i * (NSUB + 1) + NSUB) * 32;
        __hip_atomic_fetch_add(mp, 1u, __ATOMIC_RELAXED, __HIP_MEMORY_SCOPE_AGENT);
        while (__hip_atomic_load(mp, __ATOMIC_RELAXED, __HIP_MEMORY_SCOPE_AGENT)
               < (unsigned)TAILB)
            __builtin_amdgcn_s_sleep(1);
    }
    __syncthreads();
}

// init: zero cnts/bar/bitmaps/degree counters/agg buffers (~1.9 MB)
__global__ __launch_bounds__(256) void k_init(char* ws, unsigned zw) {
    unsigned t = blockIdx.x * blockDim.x + threadIdx.x;
    if (t < zw) ((uint4*)ws)[t] = make_uint4(0u, 0u, 0u, 0u);
}

__global__ __launch_bounds__(NTHR) void k_main(
        const float* __restrict__ feat, const float* __restrict__ ew,
        const int* __restrict__ src, const int* __restrict__ dst,
        const int* __restrict__ tnode, const unsigned* __restrict__ bnn,
        const float* __restrict__ W1, const float* __restrict__ b1,
        const float* __restrict__ W2, const float* __restrict__ b2,
        const float* __restrict__ W3, const float* __restrict__ b3,
        float* out,
        int* idx1, int* idx2,
        unsigned* list1, unsigned* list2, unsigned* list3,
        unsigned* cnts, unsigned* incnt, unsigned* outcnt,
        unsigned* bm1, unsigned* bm2, unsigned* bmN,
        float* agg1c, float* agg2c, unsigned* bar) {
    __shared__ unsigned s_le, s_ln, s_eb, s_nb;
    __shared__ unsigned stage[STG];
    __shared__ int stageN[STGN];

    const int tid = threadIdx.x;
    const int gid = blockIdx.x * NTHR + tid;
    const int lane = tid & 63;
    int tg[NG]; load_targets(tnode, bnn, tg);

    // ---- stage A: edges into targets -> list3; claim node2; target in-deg ----
    {
        if (tid == 0) { s_le = 0; s_ln = 0; }
        __syncthreads();
        int base = gid * EPT;
        if (base < NED) {
            int2 d2 = *(const int2*)(dst + base);
            int dd[2] = {d2.x, d2.y};
            #pragma unroll
            for (int k = 0; k < 2; k++) {
                int d = dd[k];
                int g = tgt_of(d, tg);
                if (g >= 0) {
                    int e = base + k;
                    stage[atomicAdd(&s_le, 1u)] = ((unsigned)g << 19) | (unsigned)e;
                    atomicAdd(&incnt[d], 1u);          // target in-deg
                    int s = src[e];
                    bset(bmN, s);
                    if (bclaim(bm2, s)) stageN[atomicAdd(&s_ln, 1u)] = s;
                }
            }
        }
        __syncthreads();
        if (tid == 0) {
            s_eb = s_le ? atomicAdd(&cnts[4], s_le) : 0u;
            s_nb = s_ln ? atomicAdd(&cnts[1], s_ln) : 0u;
        }
        __syncthreads();
        for (unsigned t = tid; t < s_le; t += NTHR) {
            unsigned p = s_eb + t; if (p < E3CAP) st_wt(&list3[p], stage[t]);
        }
        for (unsigned t = tid; t < s_ln; t += NTHR) {
            int s = stageN[t]; unsigned id = s_nb + t;
            st_wt(&idx2[s], id < N2CAP ? (int)id : -1);
        }
        if (blockIdx.x == 0 && tid < NG * NCLS) st_wt(&out[tid], b3[tid & 3]);
    }
    gbar(bar, 0);

    // ---- stage B: edges into node2 -> list2; claim node1; node2 in-deg ----
    {
        if (tid == 0) { s_le = 0; s_ln = 0; }
        __syncthreads();
        int base = gid * EPT;
        if (base < NED) {
            int2 d2 = *(const int2*)(dst + base);
            int dd[2] = {d2.x, d2.y};
            #pragma unroll
            for (int k = 0; k < 2; k++) {
                int d = dd[k];
                if (bt(bm2, d)) {
                    int iv = idx2[d];
                    if ((unsigned)iv < N2CAP) {
                        int e = base + k;
                        stage[atomicAdd(&s_le, 1u)] = ((unsigned)iv << 19) | (unsigned)e;
                        if (tgt_of(d, tg) < 0) atomicAdd(&incnt[d], 1u);
                        int s = src[e];
                        bset(bmN, s);
                        if (bclaim(bm1, s)) stageN[atomicAdd(&s_ln, 1u)] = s;
                    }
                }
            }
        }
        __syncthreads();
        if (tid == 0) {
            s_eb = s_le ? atomicAdd(&cnts[3], s_le) : 0u;
            s_nb = s_ln ? atomicAdd(&cnts[0], s_ln) : 0u;
        }
        __syncthreads();
        for (unsigned t = tid; t < s_le; t += NTHR) {
            unsigned p = s_eb + t; if (p < E2CAP) st_wt(&list2[p], stage[t]);
        }
        for (unsigned t = tid; t < s_ln; t += NTHR) {
            int s = stageN[t]; unsigned id = s_nb + t;
            st_wt(&idx1[s], id < N1CAP ? (int)id : -1);
        }
    }
    gbar(bar, 1);

    // ---- stage C: edges into node1 -> list1; node1-only in-deg; mark srcs ----
    {
        if (tid == 0) s_le = 0;
        __syncthreads();
        int base = gid * EPT;
        if (base < NED) {
            int2 d2 = *(const int2*)(dst + base);
            int dd[2] = {d2.x, d2.y};
            #pragma unroll
            for (int k = 0; k < 2; k++) {
                int d = dd[k];
                if (bt(bm1, d)) {
                    int iv = idx1[d];
                    if ((unsigned)iv < N1CAP) {
                        int e = base + k;
                        stage[atomicAdd(&s_le, 1u)] = ((unsigned)iv << 19) | (unsigned)e;
                        if (!bt(bm2, d) && tgt_of(d, tg) < 0) atomicAdd(&incnt[d], 1u);
                        bset(bmN, src[e]);
                    }
                }
            }
        }
        __syncthreads();
        if (tid == 0) s_eb = s_le ? atomicAdd(&cnts[2], s_le) : 0u;
        __syncthreads();
        for (unsigned t = tid; t < s_le; t += NTHR) {
            unsigned p = s_eb + t; if (p < E1CAP) st_wt(&list1[p], stage[t]);
        }
    }
    gbar(bar, 2);

    // ---- stage D: filtered out-degree (bmN test); barrier doubles as exit ----
    {
        int base = gid * EPT;
        if (base < NED) {
            int2 s2 = *(const int2*)(src + base);
            int ss[2] = {s2.x, s2.y};
            #pragma unroll
            for (int k = 0; k < 2; k++)
                if (bt(bmN, ss[k])) atomicAdd(&outcnt[ss[k]], 1u);
        }
        asm volatile("s_waitcnt vmcnt(0)" ::: "memory");
        __syncthreads();
        bool tail = blockIdx.x < TAILB;
        if (threadIdx.x == 0) {
            arrive(bar, 3);
            if (tail) waitfull(bar, 3);
        }
        if (!tail) return;
        __syncthreads();
    }

    // ---- stage E (TAILB blocks): agg1, wave per edge, 2-way ILP ----
    {
        unsigned e1 = cnts[2]; if (e1 > E1CAP) e1 = E1CAP;
        unsigned w = (unsigned)gid >> 6;
        const unsigned nw = (TAILB * NTHR) >> 6;
        for (unsigned i = w; i < e1; i += 2 * nw) {
            unsigned pk0 = list1[i];
            unsigned j2 = i + nw;
            unsigned pk1 = (j2 < e1) ? list1[j2] : 0u;
            int e0 = pk0 & EMASK; unsigned i10 = pk0 >> 19;
            float we0 = ew[e0]; int s0 = src[e0];
            int e1i = pk1 & EMASK; unsigned i11 = pk1 >> 19;
            float we1 = 0.f; int s1 = 0;
            if (j2 < e1) { we1 = ew[e1i]; s1 = src[e1i]; }
            float wt0 = we0 * rsqrtf(fmaxf((float)outcnt[s0], 1.f));
            atomicAdd(&agg1c[(size_t)i10 * F0 + lane],
                      feat[(size_t)s0 * F0 + lane] * wt0);
            if (j2 < e1) {
                float wt1 = we1 * rsqrtf(fmaxf((float)outcnt[s1], 1.f));
                atomicAdd(&agg1c[(size_t)i11 * F0 + lane],
                          feat[(size_t)s1 * F0 + lane] * wt1);
            }
        }
    }
    gbar_tail(bar, 4);

    // ---- stage G' (TAILB blocks): agg2 with h1 computed on the fly ----
    {
        unsigned e2 = cnts[3]; if (e2 > E2CAP) e2 = E2CAP;
        unsigned w = (unsigned)gid >> 6;
        const unsigned nw = (TAILB * NTHR) >> 6;
        for (unsigned i = w; i < e2; i += nw) {
            unsigned pk = list2[i];
            int e = pk & EMASK, i2 = pk >> 19;
            float we = ew[e]; int s = src[e];
            unsigned i1 = (unsigned)idx1[s]; if (i1 >= N1CAP) continue;
            float wt = we * rsqrtf(fmaxf((float)outcnt[s], 1.f));
            float innorm1 = rsqrtf(fmaxf((float)incnt[s], 1.f));
            float rv = agg1c[(size_t)i1 * F0 + lane];
            float acc0 = 0.f, acc1 = 0.f;
            #pragma unroll 8
            for (int k2 = 0; k2 < F0; k2++) {
                float bv = __shfl(rv, k2, 64);
                acc0 += bv * W1[k2 * F1 + lane];
                acc1 += bv * W1[k2 * F1 + lane + 64];
            }
            float h0 = fmaxf(acc0 * innorm1 + b1[lane], 0.f) * wt;
            float h1v = fmaxf(acc1 * innorm1 + b1[lane + 64], 0.f) * wt;
            atomicAdd(&agg2c[(size_t)i2 * F1 + lane], h0);
            atomicAdd(&agg2c[(size_t)i2 * F1 + lane + 64], h1v);
        }
    }
    gbar_tail(bar, 5);

    // ---- stage I' (TAILB blocks): out += (h2-on-the-fly . W3) per e3-edge ----
    {
        unsigned e3 = cnts[4]; if (e3 > E3CAP) e3 = E3CAP;
        unsigned w = (unsigned)gid >> 6;
        const unsigned nw = (TAILB * NTHR) >> 6;
        for (unsigned i = w; i < e3; i += nw) {
            unsigned pk = list3[i];
            int e = pk & EMASK, g = pk >> 19;
            float we = ew[e]; int s = src[e];
            unsigned i2 = (unsigned)idx2[s]; if (i2 >= N2CAP) continue;
            float wt = we * rsqrtf(fmaxf((float)outcnt[s], 1.f))
                          * rsqrtf(fmaxf((float)incnt[tg[g]], 1.f));
            float innorm2 = rsqrtf(fmaxf((float)incnt[s], 1.f));
            float rv0 = agg2c[(size_t)i2 * F1 + lane];
            float rv1 = agg2c[(size_t)i2 * F1 + lane + 64];
            float acc0 = 0.f, acc1 = 0.f;
            #pragma unroll 8
            for (int k2 = 0; k2 < 64; k2++) {
                float bv = __shfl(rv0, k2, 64);
                acc0 += bv * W2[k2 * F1 + lane];
                acc1 += bv * W2[k2 * F1 + lane + 64];
            }
            #pragma unroll 8
            for (int k2 = 0; k2 < 64; k2++) {
                float bv = __shfl(rv1, k2, 64);
                acc0 += bv * W2[(k2 + 64) * F1 + lane];
                acc1 += bv * W2[(k2 + 64) * F1 + lane + 64];
            }
            float h20 = fmaxf(acc0 * innorm2 + b2[lane], 0.f);
            float h21 = fmaxf(acc1 * innorm2 + b2[lane + 64], 0.f);
            float oc0 = (h20 * W3[lane * NCLS + 0] + h21 * W3[(lane + 64) * NCLS + 0]) * wt;
            float oc1 = (h20 * W3[lane * NCLS + 1] + h21 * W3[(lane + 64) * NCLS + 1]) * wt;
            float oc2 = (h20 * W3[lane * NCLS + 2] + h21 * W3[(lane + 64) * NCLS + 2]) * wt;
            float oc3 = (h20 * W3[lane * NCLS + 3] + h21 * W3[(lane + 64) * NCLS + 3]) * wt;
            #pragma unroll
            for (int off = 32; off; off >>= 1) {
                oc0 += __shfl_down(oc0, off, 64);
                oc1 += __shfl_down(oc1, off, 64);
                oc2 += __shfl_down(oc2, off, 64);
                oc3 += __shfl_down(oc3, off, 64);
            }
            if (lane == 0) {
                atomicAdd(&out[g * NCLS + 0], oc0);
                atomicAdd(&out[g * NCLS + 1], oc1);
                atomicAdd(&out[g * NCLS + 2], oc2);
                atomicAdd(&out[g * NCLS + 3], oc3);
            }
        }
    }
}

extern "C" void kernel_launch(void* const* d_in, const int* in_sizes, int n_in,
                              void* d_out, int out_size, void* d_ws, size_t ws_size,
                              hipStream_t stream) {
    const float* in_feat = (const float*)d_in[0];
    const float* ew      = (const float*)d_in[1];
    const int*   src     = (const int*)d_in[2];
    const int*   dst     = (const int*)d_in[3];
    const unsigned* bnn  = (const unsigned*)d_in[4];
    const int*   tnode   = (const int*)d_in[5];
    const float* W1 = (const float*)d_in[6];
    const float* b1 = (const float*)d_in[7];
    const float* W2 = (const float*)d_in[8];
    const float* b2 = (const float*)d_in[9];
    const float* W3 = (const float*)d_in[10];
    const float* b3 = (const float*)d_in[11];
    float* out = (float*)d_out;
    (void)in_sizes; (void)n_in; (void)out_size; (void)ws_size;

    char* ws = (char*)d_ws;
    size_t o = 0;
    auto alloc = [&](size_t bytes) { size_t r = o; o += (bytes + 255) & ~(size_t)255; return r; };

    // --- region zeroed by k_init ---
    size_t off_cnts  = alloc(8 * 4);
    size_t off_bar   = alloc((size_t)NBAR * (NSUB + 1) * 32 * 4);
    size_t off_bm1   = alloc((size_t)BMW * 4);
    size_t off_bm2   = alloc((size_t)BMW * 4);
    size_t off_bmN   = alloc((size_t)BMW * 4);
    size_t off_inc   = alloc((size_t)NND * 4);
    size_t off_outc  = alloc((size_t)NND * 4);
    size_t off_agg1  = alloc((size_t)N1CAP * F0 * 4);
    size_t off_agg2  = alloc((size_t)N2CAP * F1 * 4);
    size_t init_bytes = o;
    // --- write-before-read region ---
    size_t off_idx2  = alloc((size_t)NND * 4);
    size_t off_idx1  = alloc((size_t)NND * 4);
    size_t off_list3 = alloc((size_t)E3CAP * 4);
    size_t off_list2 = alloc((size_t)E2CAP * 4);
    size_t off_list1 = alloc((size_t)E1CAP * 4);

    unsigned* cnts    = (unsigned*)(ws + off_cnts);
    unsigned* bar     = (unsigned*)(ws + off_bar);
    unsigned* bm1     = (unsigned*)(ws + off_bm1);
    unsigned* bm2     = (unsigned*)(ws + off_bm2);
    unsigned* bmN     = (unsigned*)(ws + off_bmN);
    unsigned* incnt   = (unsigned*)(ws + off_inc);
    unsigned* outcnt  = (unsigned*)(ws + off_outc);
    float*    agg1c   = (float*)(ws + off_agg1);
    float*    agg2c   = (float*)(ws + off_agg2);
    int*      idx2    = (int*)(ws + off_idx2);
    int*      idx1    = (int*)(ws + off_idx1);
    unsigned* list3   = (unsigned*)(ws + off_list3);
    unsigned* list2   = (unsigned*)(ws + off_list2);
    unsigned* list1   = (unsigned*)(ws + off_list1);

    unsigned zw = (unsigned)(init_bytes / 16);
    k_init<<<(int)((zw + 255) / 256), 256, 0, stream>>>(ws, zw);

    k_main<<<NBLK, NTHR, 0, stream>>>(in_feat, ew, src, dst, tnode, bnn,
                                      W1, b1, W2, b2, W3, b3, out,
                                      idx1, idx2, list1, list2, list3,
                                      cnts, incnt, outcnt, bm1, bm2, bmN,
                                      agg1c, agg2c, bar);
}

// Round 14
// 66.546 us; speedup vs baseline: 1.2941x; 1.0093x over previous
//
#include <hip/hip_runtime.h>

#define NND 50000
#define NED 500000
#define F0 64
#define F1 128
#define NCLS 4
#define NG 8

#define NBLK 256
#define NTHR 1024
#define EPT 2           // NBLK*NTHR*EPT = 524288 >= NED
#define NBAR 8
#define NSUB 16         // arrival sub-counters per barrier (16 blocks each)
#define STG 2048        // per-block edge-hit staging (= NTHR*EPT worst case)
#define STGN 2048
#define BMW ((NND + 31) / 32)
#define EMASK 0x7FFFFu  // e < 2^19 (NED=500000 < 524288)

// capacities (expected: n2~80, e3~80, e2~800, n1~800, e1~8000)
#define N1CAP 4096
#define N2CAP 1024
#define E1CAP 32768
#define E2CAP 8192
#define E3CAP 2048

// cnts: [0]=n1 [1]=n2 [2]=e1 [3]=e2 [4]=e3

// write-through store: bypasses non-coherent per-XCD L2, so cross-phase
// readers on other XCDs see it without any cache flush. Safe because no XCD
// normal-reads a line before its FINAL write (audited per buffer).
template <typename T>
__device__ __forceinline__ void st_wt(T* p, T v) {
    __hip_atomic_store(p, v, __ATOMIC_RELAXED, __HIP_MEMORY_SCOPE_AGENT);
}

__device__ __forceinline__ bool bt(const unsigned* __restrict__ bm, int n) {
    return (bm[n >> 5] >> (n & 31)) & 1u;
}
__device__ __forceinline__ void bset(unsigned* bm, int n) {
    atomicOr(&bm[n >> 5], 1u << (n & 31));
}

__device__ __forceinline__ void load_targets(const int* __restrict__ tnode,
                                             const unsigned* __restrict__ bnn,
                                             int* t) {
    bool is64 = true;
    #pragma unroll
    for (int k = 0; k < 4; k++) if (bnn[2 * k + 1] != 0u) { is64 = false; break; }
    long long off = 0;
    #pragma unroll
    for (int g = 0; g < NG; g++) {
        t[g] = tnode[g] + (int)off;
        off += is64 ? (long long)bnn[2 * g] : (long long)(int)bnn[g];
    }
}

__device__ __forceinline__ int tgt_of(int d, const int* t) {
    int g = -1;
    #pragma unroll
    for (int k = 0; k < NG; k++) if (d == t[k]) g = k;
    return g;
}

// Fence-free FLAT grid barrier: write-through data + vmcnt drain before
// s_barrier (R7-R13-proven memory semantics). Arrival = one RMW on the
// block's sub-line (<=16 serialized/line). Detection = leader sums all NSUB
// sub-counters with independent relaxed loads (one latency per poll, no
// master-counter dependent hop).
__device__ __forceinline__ void gbar(unsigned* bar, int i) {
    asm volatile("s_waitcnt vmcnt(0)" ::: "memory");
    __syncthreads();
    if (threadIdx.x == 0) {
        unsigned* base = bar + (size_t)i * NSUB * 32;
        __hip_atomic_fetch_add(base + (blockIdx.x & (NSUB - 1)) * 32, 1u,
                               __ATOMIC_RELAXED, __HIP_MEMORY_SCOPE_AGENT);
        for (;;) {
            unsigned s = 0;
            #pragma unroll
            for (int k = 0; k < NSUB; k++)
                s += __hip_atomic_load(base + k * 32, __ATOMIC_RELAXED,
                                       __HIP_MEMORY_SCOPE_AGENT);
            if (s == (unsigned)NBLK) break;
            __builtin_amdgcn_s_sleep(1);
        }
    }
    __syncthreads();
}

// workspace init: zero region + 0xFF region, 16B stores
__global__ __launch_bounds__(256) void k_init(char* ws, unsigned zw, unsigned foff, unsigned fw) {
    unsigned t = blockIdx.x * blockDim.x + threadIdx.x;
    if (t < zw) ((uint4*)ws)[t] = make_uint4(0u, 0u, 0u, 0u);
    if (t < fw) ((uint4*)(ws + foff))[t] = make_uint4(~0u, ~0u, ~0u, ~0u);
}

__global__ __launch_bounds__(NTHR) void k_main(
        const float* __restrict__ feat, const float* __restrict__ ew,
        const int* __restrict__ src, const int* __restrict__ dst,
        const int* __restrict__ tnode, const unsigned* __restrict__ bnn,
        const float* __restrict__ W1, const float* __restrict__ b1,
        const float* __restrict__ W2, const float* __restrict__ b2,
        const float* __restrict__ W3, const float* __restrict__ b3,
        float* out,
        int* idx1, int* idx2,
        unsigned* list1, unsigned* list2, unsigned* list3,
        unsigned* cnts, unsigned* incnt, unsigned* outcnt,
        unsigned* bm1, unsigned* bm2, unsigned* bmN,
        float* agg1c, float* agg2c, unsigned* bar) {
    __shared__ unsigned s_le, s_ln, s_eb, s_nb;
    __shared__ unsigned stage[STG];
    __shared__ int stageN[STGN];

    const int tid = threadIdx.x;
    const int gid = blockIdx.x * NTHR + tid;
    const int lane = tid & 63;
    int tg[NG]; load_targets(tnode, bnn, tg);

    // ---- phase A: edges into targets -> list3 {g|e}; claim node2; tgt in-deg ----
    {
        if (tid == 0) { s_le = 0; s_ln = 0; }
        __syncthreads();
        int base = gid * EPT;
        if (base < NED) {
            int2 d2 = *(const int2*)(dst + base);
            int dd[2] = {d2.x, d2.y};
            #pragma unroll
            for (int k = 0; k < 2; k++) {
                int d = dd[k];
                int g = tgt_of(d, tg);
                if (g >= 0) {
                    int e = base + k;
                    stage[atomicAdd(&s_le, 1u)] = ((unsigned)g << 19) | (unsigned)e;
                    atomicAdd(&incnt[d], 1u);
                    int s = src[e];
                    bset(bmN, s);
                    if (atomicCAS(&idx2[s], -1, -2) == -1) {
                        bset(bm2, s);
                        stageN[atomicAdd(&s_ln, 1u)] = s;
                    }
                }
            }
        }
        __syncthreads();
        if (tid == 0) {
            s_eb = s_le ? atomicAdd(&cnts[4], s_le) : 0u;
            s_nb = s_ln ? atomicAdd(&cnts[1], s_ln) : 0u;
        }
        __syncthreads();
        for (unsigned t = tid; t < s_le; t += NTHR) {
            unsigned p = s_eb + t; if (p < E3CAP) st_wt(&list3[p], stage[t]);
        }
        for (unsigned t = tid; t < s_ln; t += NTHR) {
            int s = stageN[t]; unsigned id = s_nb + t;
            st_wt(&idx2[s], id < N2CAP ? (int)id : -1);
        }
        if (blockIdx.x == 0 && tid < NG * NCLS) st_wt(&out[tid], b3[tid & 3]);
    }
    gbar(bar, 0);

    // ---- phase B: edges into node2 -> list2 {i2|e}; claim node1 ----
    {
        if (tid == 0) { s_le = 0; s_ln = 0; }
        __syncthreads();
        int base = gid * EPT;
        if (base < NED) {
            int2 d2 = *(const int2*)(dst + base);
            int dd[2] = {d2.x, d2.y};
            #pragma unroll
            for (int k = 0; k < 2; k++) {
                int d = dd[k];
                if (bt(bm2, d)) {
                    int iv = idx2[d];
                    if (iv >= 0) {
                        int e = base + k;
                        stage[atomicAdd(&s_le, 1u)] = ((unsigned)iv << 19) | (unsigned)e;
                        if (tgt_of(d, tg) < 0) atomicAdd(&incnt[d], 1u);
                        int s = src[e];
                        bset(bmN, s);
                        if (atomicCAS(&idx1[s], -1, -2) == -1) {
                            bset(bm1, s);
                            stageN[atomicAdd(&s_ln, 1u)] = s;
                        }
                    }
                }
            }
        }
        __syncthreads();
        if (tid == 0) {
            s_eb = s_le ? atomicAdd(&cnts[3], s_le) : 0u;
            s_nb = s_ln ? atomicAdd(&cnts[0], s_ln) : 0u;
        }
        __syncthreads();
        for (unsigned t = tid; t < s_le; t += NTHR) {
            unsigned p = s_eb + t; if (p < E2CAP) st_wt(&list2[p], stage[t]);
        }
        for (unsigned t = tid; t < s_ln; t += NTHR) {
            int s = stageN[t]; unsigned id = s_nb + t;
            st_wt(&idx1[s], id < N1CAP ? (int)id : -1);
        }
    }
    gbar(bar, 1);

    // ---- phase C: edges into node1 -> list1 {i1|e}; node1-only in-deg ----
    {
        if (tid == 0) s_le = 0;
        __syncthreads();
        int base = gid * EPT;
        if (base < NED) {
            int2 d2 = *(const int2*)(dst + base);
            int dd[2] = {d2.x, d2.y};
            #pragma unroll
            for (int k = 0; k < 2; k++) {
                int d = dd[k];
                if (bt(bm1, d)) {
                    int iv = idx1[d];
                    if (iv >= 0) {
                        int e = base + k;
                        stage[atomicAdd(&s_le, 1u)] = ((unsigned)iv << 19) | (unsigned)e;
                        if (idx2[d] < 0 && tgt_of(d, tg) < 0) atomicAdd(&incnt[d], 1u);
                        bset(bmN, src[e]);
                    }
                }
            }
        }
        __syncthreads();
        if (tid == 0) s_eb = s_le ? atomicAdd(&cnts[2], s_le) : 0u;
        __syncthreads();
        for (unsigned t = tid; t < s_le; t += NTHR) {
            unsigned p = s_eb + t; if (p < E1CAP) st_wt(&list1[p], stage[t]);
        }
    }
    gbar(bar, 2);

    // ---- phase D: filtered out-degree (bmN test) ----
    {
        int base = gid * EPT;
        if (base < NED) {
            int2 s2 = *(const int2*)(src + base);
            int ss[2] = {s2.x, s2.y};
            #pragma unroll
            for (int k = 0; k < 2; k++)
                if (bt(bmN, ss[k])) atomicAdd(&outcnt[ss[k]], 1u);
        }
    }
    gbar(bar, 3);

    // ---- phase E: agg1 (wave per edge, packed list, 2-way ILP) ----
    {
        unsigned e1 = cnts[2]; if (e1 > E1CAP) e1 = E1CAP;
        unsigned w = (unsigned)gid >> 6;
        const unsigned nw = (NBLK * NTHR) >> 6;
        for (unsigned i = w; i < e1; i += 2 * nw) {
            unsigned pk0 = list1[i];
            unsigned j2 = i + nw;
            unsigned pk1 = (j2 < e1) ? list1[j2] : 0u;
            int e0 = pk0 & EMASK, i10 = pk0 >> 19;
            float we0 = ew[e0]; int s0 = src[e0];
            int e1i = pk1 & EMASK, i11 = pk1 >> 19;
            float we1 = 0.f; int s1 = 0;
            if (j2 < e1) { we1 = ew[e1i]; s1 = src[e1i]; }
            float wt0 = we0 * rsqrtf(fmaxf((float)outcnt[s0], 1.f));
            atomicAdd(&agg1c[(size_t)i10 * F0 + lane],
                      feat[(size_t)s0 * F0 + lane] * wt0);
            if (j2 < e1) {
                float wt1 = we1 * rsqrtf(fmaxf((float)outcnt[s1], 1.f));
                atomicAdd(&agg1c[(size_t)i11 * F0 + lane],
                          feat[(size_t)s1 * F0 + lane] * wt1);
            }
        }
    }
    gbar(bar, 4);

    // ---- phase G': agg2 with h1 computed on the fly (wave per edge) ----
    {
        unsigned e2 = cnts[3]; if (e2 > E2CAP) e2 = E2CAP;
        unsigned w = (unsigned)gid >> 6;
        const unsigned nw = (NBLK * NTHR) >> 6;
        for (unsigned i = w; i < e2; i += nw) {
            unsigned pk = list2[i];
            int e = pk & EMASK, i2 = pk >> 19;
            float we = ew[e]; int s = src[e];
            int i1 = idx1[s]; if (i1 < 0) continue;
            float wt = we * rsqrtf(fmaxf((float)outcnt[s], 1.f));
            float innorm1 = rsqrtf(fmaxf((float)incnt[s], 1.f));
            float rv = agg1c[(size_t)i1 * F0 + lane];
            float acc0 = 0.f, acc1 = 0.f;
            #pragma unroll 8
            for (int k2 = 0; k2 < F0; k2++) {
                float bv = __shfl(rv, k2, 64);
                acc0 += bv * W1[k2 * F1 + lane];
                acc1 += bv * W1[k2 * F1 + lane + 64];
            }
            float h0 = fmaxf(acc0 * innorm1 + b1[lane], 0.f) * wt;
            float h1v = fmaxf(acc1 * innorm1 + b1[lane + 64], 0.f) * wt;
            atomicAdd(&agg2c[(size_t)i2 * F1 + lane], h0);
            atomicAdd(&agg2c[(size_t)i2 * F1 + lane + 64], h1v);
        }
    }
    gbar(bar, 5);

    // ---- phase I': out += (h2-on-the-fly . W3) per e3-edge (wave per edge) ----
    {
        unsigned e3 = cnts[4]; if (e3 > E3CAP) e3 = E3CAP;
        unsigned w = (unsigned)gid >> 6;
        const unsigned nw = (NBLK * NTHR) >> 6;
        for (unsigned i = w; i < e3; i += nw) {
            unsigned pk = list3[i];
            int e = pk & EMASK, g = pk >> 19;
            float we = ew[e]; int s = src[e];
            int i2 = idx2[s]; if (i2 < 0) continue;
            float wt = we * rsqrtf(fmaxf((float)outcnt[s], 1.f))
                          * rsqrtf(fmaxf((float)incnt[tg[g]], 1.f));
            float innorm2 = rsqrtf(fmaxf((float)incnt[s], 1.f));
            float rv0 = agg2c[(size_t)i2 * F1 + lane];
            float rv1 = agg2c[(size_t)i2 * F1 + lane + 64];
            float acc0 = 0.f, acc1 = 0.f;
            #pragma unroll 8
            for (int k2 = 0; k2 < 64; k2++) {
                float bv = __shfl(rv0, k2, 64);
                acc0 += bv * W2[k2 * F1 + lane];
                acc1 += bv * W2[k2 * F1 + lane + 64];
            }
            #pragma unroll 8
            for (int k2 = 0; k2 < 64; k2++) {
                float bv = __shfl(rv1, k2, 64);
                acc0 += bv * W2[(k2 + 64) * F1 + lane];
                acc1 += bv * W2[(k2 + 64) * F1 + lane + 64];
            }
            float h20 = fmaxf(acc0 * innorm2 + b2[lane], 0.f);
            float h21 = fmaxf(acc1 * innorm2 + b2[lane + 64], 0.f);
            float oc0 = (h20 * W3[lane * NCLS + 0] + h21 * W3[(lane + 64) * NCLS + 0]) * wt;
            float oc1 = (h20 * W3[lane * NCLS + 1] + h21 * W3[(lane + 64) * NCLS + 1]) * wt;
            float oc2 = (h20 * W3[lane * NCLS + 2] + h21 * W3[(lane + 64) * NCLS + 2]) * wt;
            float oc3 = (h20 * W3[lane * NCLS + 3] + h21 * W3[(lane + 64) * NCLS + 3]) * wt;
            #pragma unroll
            for (int off = 32; off; off >>= 1) {
                oc0 += __shfl_down(oc0, off, 64);
                oc1 += __shfl_down(oc1, off, 64);
                oc2 += __shfl_down(oc2, off, 64);
                oc3 += __shfl_down(oc3, off, 64);
            }
            if (lane == 0) {
                atomicAdd(&out[g * NCLS + 0], oc0);
                atomicAdd(&out[g * NCLS + 1], oc1);
                atomicAdd(&out[g * NCLS + 2], oc2);
                atomicAdd(&out[g * NCLS + 3], oc3);
            }
        }
    }
}

extern "C" void kernel_launch(void* const* d_in, const int* in_sizes, int n_in,
                              void* d_out, int out_size, void* d_ws, size_t ws_size,
                              hipStream_t stream) {
    const float* in_feat = (const float*)d_in[0];
    const float* ew      = (const float*)d_in[1];
    const int*   src     = (const int*)d_in[2];
    const int*   dst     = (const int*)d_in[3];
    const unsigned* bnn  = (const unsigned*)d_in[4];
    const int*   tnode   = (const int*)d_in[5];
    const float* W1 = (const float*)d_in[6];
    const float* b1 = (const float*)d_in[7];
    const float* W2 = (const float*)d_in[8];
    const float* b2 = (const float*)d_in[9];
    const float* W3 = (const float*)d_in[10];
    const float* b3 = (const float*)d_in[11];
    float* out = (float*)d_out;
    (void)in_sizes; (void)n_in; (void)out_size; (void)ws_size;

    char* ws = (char*)d_ws;
    size_t o = 0;
    auto alloc = [&](size_t bytes) { size_t r = o; o += (bytes + 255) & ~(size_t)255; return r; };

    // --- zero-init region (starts at 0) ---
    size_t off_outcnt = alloc((size_t)NND * 4);
    size_t off_incnt  = alloc((size_t)NND * 4);
    size_t off_cnts   = alloc(8 * 4);
    size_t off_bar    = alloc((size_t)NBAR * NSUB * 32 * 4);
    size_t off_bm1    = alloc((size_t)BMW * 4);
    size_t off_bm2    = alloc((size_t)BMW * 4);
    size_t off_bmN    = alloc((size_t)BMW * 4);
    size_t off_agg1   = alloc((size_t)N1CAP * F0 * 4);
    size_t off_agg2   = alloc((size_t)N2CAP * F1 * 4);
    size_t zero_bytes = o;
    // --- 0xFF-init region ---
    size_t ff_start = o;
    size_t off_idx2   = alloc((size_t)NND * 4);
    size_t off_idx1   = alloc((size_t)NND * 4);
    size_t ff_bytes = o - ff_start;
    // --- write-before-read region ---
    size_t off_list3   = alloc((size_t)E3CAP * 4);
    size_t off_list2   = alloc((size_t)E2CAP * 4);
    size_t off_list1   = alloc((size_t)E1CAP * 4);

    unsigned* outcnt  = (unsigned*)(ws + off_outcnt);
    unsigned* incnt   = (unsigned*)(ws + off_incnt);
    unsigned* cnts    = (unsigned*)(ws + off_cnts);
    unsigned* bar     = (unsigned*)(ws + off_bar);
    unsigned* bm1     = (unsigned*)(ws + off_bm1);
    unsigned* bm2     = (unsigned*)(ws + off_bm2);
    unsigned* bmN     = (unsigned*)(ws + off_bmN);
    float*    agg1c   = (float*)(ws + off_agg1);
    float*    agg2c   = (float*)(ws + off_agg2);
    int*      idx2    = (int*)(ws + off_idx2);
    int*      idx1    = (int*)(ws + off_idx1);
    unsigned* list3   = (unsigned*)(ws + off_list3);
    unsigned* list2   = (unsigned*)(ws + off_list2);
    unsigned* list1   = (unsigned*)(ws + off_list1);

    unsigned zw = (unsigned)(zero_bytes / 16);
    unsigned fw = (unsigned)(ff_bytes / 16);
    unsigned iw = zw > fw ? zw : fw;
    k_init<<<(int)((iw + 255) / 256), 256, 0, stream>>>(ws, zw, (unsigned)ff_start, fw);

    k_main<<<NBLK, NTHR, 0, stream>>>(in_feat, ew, src, dst, tnode, bnn,
                                      W1, b1, W2, b2, W3, b3, out,
                                      idx1, idx2, list1, list2, list3,
                                      cnts, incnt, outcnt, bm1, bm2, bmN,
                                      agg1c, agg2c, bar);
}

// Round 15
// 63.720 us; speedup vs baseline: 1.3515x; 1.0443x over previous
//
#include <hip/hip_runtime.h>

#define NND 50000
#define NED 500000
#define F0 64
#define F1 128
#define NCLS 4
#define NG 8

#define NBLK 256
#define NTHR 1024
#define EPT 2           // NBLK*NTHR*EPT = 524288 >= NED
#define NBAR 8
#define NSUB 8
#define STG 2048        // per-block edge-hit staging (= NTHR*EPT worst case)
#define STGN 2048
#define BMW ((NND + 31) / 32)
#define EMASK 0x7FFFFu  // e < 2^19 (NED=500000 < 524288)

// capacities (expected: n2~80, e3~80, e2~800, n1~800, e1~8000)
#define N1CAP 4096
#define N2CAP 1024
#define E1CAP 32768
#define E2CAP 8192
#define E3CAP 2048

// cnts: [0]=n1 [1]=n2 [2]=e1 [3]=e2 [4]=e3

// write-through store: goes to the coherence point; safe because within this
// kernel no XCD normal-reads a line before its FINAL write (audited per buffer),
// and kernel-boundary flushes handle everything else.
template <typename T>
__device__ __forceinline__ void st_wt(T* p, T v) {
    __hip_atomic_store(p, v, __ATOMIC_RELAXED, __HIP_MEMORY_SCOPE_AGENT);
}

__device__ __forceinline__ bool bt(const unsigned* __restrict__ bm, int n) {
    return (bm[n >> 5] >> (n & 31)) & 1u;
}
__device__ __forceinline__ void bset(unsigned* bm, int n) {
    atomicOr(&bm[n >> 5], 1u << (n & 31));
}

__device__ __forceinline__ void load_targets(const int* __restrict__ tnode,
                                             const unsigned* __restrict__ bnn,
                                             int* t) {
    bool is64 = true;
    #pragma unroll
    for (int k = 0; k < 4; k++) if (bnn[2 * k + 1] != 0u) { is64 = false; break; }
    long long off = 0;
    #pragma unroll
    for (int g = 0; g < NG; g++) {
        t[g] = tnode[g] + (int)off;
        off += is64 ? (long long)bnn[2 * g] : (long long)(int)bnn[g];
    }
}

__device__ __forceinline__ int tgt_of(int d, const int* t) {
    int g = -1;
    #pragma unroll
    for (int k = 0; k < NG; k++) if (d == t[k]) g = k;
    return g;
}

// Fence-free grid barrier (R7-R9-proven best variant): write-through data +
// vmcnt drain before s_barrier; two-level arrival (8 sub-lines -> master);
// all leaders poll ONE read-shared master line.
__device__ __forceinline__ void gbar(unsigned* bar, int i) {
    asm volatile("s_waitcnt vmcnt(0)" ::: "memory");
    __syncthreads();
    if (threadIdx.x == 0) {
        unsigned* sp = bar + (size_t)(i * (NSUB + 1) + (blockIdx.x & (NSUB - 1))) * 32;
        unsigned* mp = bar + (size_t)(i * (NSUB + 1) + NSUB) * 32;
        unsigned old = __hip_atomic_fetch_add(sp, 1u, __ATOMIC_RELAXED,
                                              __HIP_MEMORY_SCOPE_AGENT);
        if (old + 1u == (unsigned)(NBLK / NSUB))
            __hip_atomic_fetch_add(mp, 1u, __ATOMIC_RELAXED, __HIP_MEMORY_SCOPE_AGENT);
        while (__hip_atomic_load(mp, __ATOMIC_RELAXED, __HIP_MEMORY_SCOPE_AGENT)
               < (unsigned)NSUB)
            __builtin_amdgcn_s_sleep(1);
    }
    __syncthreads();
}

// workspace init: zero region + 0xFF region, 16B stores (agg buffers are
// zeroed lazily at claim time inside k_main — not here)
__global__ __launch_bounds__(256) void k_init(char* ws, unsigned zw, unsigned foff, unsigned fw) {
    unsigned t = blockIdx.x * blockDim.x + threadIdx.x;
    if (t < zw) ((uint4*)ws)[t] = make_uint4(0u, 0u, 0u, 0u);
    if (t < fw) ((uint4*)(ws + foff))[t] = make_uint4(~0u, ~0u, ~0u, ~0u);
}

__global__ __launch_bounds__(NTHR) void k_main(
        const float* __restrict__ feat, const float* __restrict__ ew,
        const int* __restrict__ src, const int* __restrict__ dst,
        const int* __restrict__ tnode, const unsigned* __restrict__ bnn,
        const float* __restrict__ W1, const float* __restrict__ b1,
        const float* __restrict__ W2, const float* __restrict__ b2,
        const float* __restrict__ W3, const float* __restrict__ b3,
        float* out,
        int* idx1, int* idx2,
        unsigned* list1, unsigned* list2, unsigned* list3,
        unsigned* cnts, unsigned* incnt, unsigned* outcnt,
        unsigned* bm1, unsigned* bm2, unsigned* bmN,
        float* agg1c, float* agg2c, unsigned* bar) {
    __shared__ unsigned s_le, s_ln, s_eb, s_nb;
    __shared__ unsigned stage[STG];
    __shared__ int stageN[STGN];

    const int tid = threadIdx.x;
    const int gid = blockIdx.x * NTHR + tid;
    const int lane = tid & 63;
    int tg[NG]; load_targets(tnode, bnn, tg);

    // ---- phase A: edges into targets -> list3 {g|e}; claim node2; tgt in-deg ----
    {
        if (tid == 0) { s_le = 0; s_ln = 0; }
        __syncthreads();
        int base = gid * EPT;
        if (base < NED) {
            int2 d2 = *(const int2*)(dst + base);
            int dd[2] = {d2.x, d2.y};
            #pragma unroll
            for (int k = 0; k < 2; k++) {
                int d = dd[k];
                int g = tgt_of(d, tg);
                if (g >= 0) {
                    int e = base + k;
                    stage[atomicAdd(&s_le, 1u)] = ((unsigned)g << 19) | (unsigned)e;
                    atomicAdd(&incnt[d], 1u);
                    int s = src[e];
                    bset(bmN, s);
                    if (atomicCAS(&idx2[s], -1, -2) == -1) {
                        bset(bm2, s);
                        stageN[atomicAdd(&s_ln, 1u)] = s;
                    }
                }
            }
        }
        __syncthreads();
        if (tid == 0) {
            s_eb = s_le ? atomicAdd(&cnts[4], s_le) : 0u;
            s_nb = s_ln ? atomicAdd(&cnts[1], s_ln) : 0u;
        }
        __syncthreads();
        for (unsigned t = tid; t < s_le; t += NTHR) {
            unsigned p = s_eb + t; if (p < E3CAP) st_wt(&list3[p], stage[t]);
        }
        for (unsigned t = tid; t < s_ln; t += NTHR) {
            int s = stageN[t]; unsigned id = s_nb + t;
            if (id < N2CAP) {
                st_wt(&idx2[s], (int)id);
                // lazy zero of this node's agg2 row (uniquely owned; first
                // atomicAdd to it is in phase G', >=4 barriers later)
                unsigned long long* rp = (unsigned long long*)&agg2c[(size_t)id * F1];
                #pragma unroll
                for (int k = 0; k < F1 / 2; k++) st_wt(&rp[k], 0ULL);
            } else st_wt(&idx2[s], -1);
        }
        if (blockIdx.x == 0 && tid < NG * NCLS) st_wt(&out[tid], b3[tid & 3]);
    }
    gbar(bar, 0);

    // ---- phase B: edges into node2 -> list2 {i2|e}; claim node1 ----
    {
        if (tid == 0) { s_le = 0; s_ln = 0; }
        __syncthreads();
        int base = gid * EPT;
        if (base < NED) {
            int2 d2 = *(const int2*)(dst + base);
            int dd[2] = {d2.x, d2.y};
            #pragma unroll
            for (int k = 0; k < 2; k++) {
                int d = dd[k];
                if (bt(bm2, d)) {
                    int iv = idx2[d];
                    if (iv >= 0) {
                        int e = base + k;
                        stage[atomicAdd(&s_le, 1u)] = ((unsigned)iv << 19) | (unsigned)e;
                        if (tgt_of(d, tg) < 0) atomicAdd(&incnt[d], 1u);
                        int s = src[e];
                        bset(bmN, s);
                        if (atomicCAS(&idx1[s], -1, -2) == -1) {
                            bset(bm1, s);
                            stageN[atomicAdd(&s_ln, 1u)] = s;
                        }
                    }
                }
            }
        }
        __syncthreads();
        if (tid == 0) {
            s_eb = s_le ? atomicAdd(&cnts[3], s_le) : 0u;
            s_nb = s_ln ? atomicAdd(&cnts[0], s_ln) : 0u;
        }
        __syncthreads();
        for (unsigned t = tid; t < s_le; t += NTHR) {
            unsigned p = s_eb + t; if (p < E2CAP) st_wt(&list2[p], stage[t]);
        }
        for (unsigned t = tid; t < s_ln; t += NTHR) {
            int s = stageN[t]; unsigned id = s_nb + t;
            if (id < N1CAP) {
                st_wt(&idx1[s], (int)id);
                // lazy zero of this node's agg1 row (first atomicAdd: phase E)
                unsigned long long* rp = (unsigned long long*)&agg1c[(size_t)id * F0];
                #pragma unroll
                for (int k = 0; k < F0 / 2; k++) st_wt(&rp[k], 0ULL);
            } else st_wt(&idx1[s], -1);
        }
    }
    gbar(bar, 1);

    // ---- phase C: edges into node1 -> list1 {i1|e}; node1-only in-deg ----
    {
        if (tid == 0) s_le = 0;
        __syncthreads();
        int base = gid * EPT;
        if (base < NED) {
            int2 d2 = *(const int2*)(dst + base);
            int dd[2] = {d2.x, d2.y};
            #pragma unroll
            for (int k = 0; k < 2; k++) {
                int d = dd[k];
                if (bt(bm1, d)) {
                    int iv = idx1[d];
                    if (iv >= 0) {
                        int e = base + k;
                        stage[atomicAdd(&s_le, 1u)] = ((unsigned)iv << 19) | (unsigned)e;
                        if (idx2[d] < 0 && tgt_of(d, tg) < 0) atomicAdd(&incnt[d], 1u);
                        bset(bmN, src[e]);
                    }
                }
            }
        }
        __syncthreads();
        if (tid == 0) s_eb = s_le ? atomicAdd(&cnts[2], s_le) : 0u;
        __syncthreads();
        for (unsigned t = tid; t < s_le; t += NTHR) {
            unsigned p = s_eb + t; if (p < E1CAP) st_wt(&list1[p], stage[t]);
        }
    }
    gbar(bar, 2);

    // ---- phase D: filtered out-degree (bmN test) ----
    {
        int base = gid * EPT;
        if (base < NED) {
            int2 s2 = *(const int2*)(src + base);
            int ss[2] = {s2.x, s2.y};
            #pragma unroll
            for (int k = 0; k < 2; k++)
                if (bt(bmN, ss[k])) atomicAdd(&outcnt[ss[k]], 1u);
        }
    }
    gbar(bar, 3);

    // ---- phase E: agg1 (wave per edge, packed list, 2-way ILP) ----
    {
        unsigned e1 = cnts[2]; if (e1 > E1CAP) e1 = E1CAP;
        unsigned w = (unsigned)gid >> 6;
        const unsigned nw = (NBLK * NTHR) >> 6;
        for (unsigned i = w; i < e1; i += 2 * nw) {
            unsigned pk0 = list1[i];
            unsigned j2 = i + nw;
            unsigned pk1 = (j2 < e1) ? list1[j2] : 0u;
            int e0 = pk0 & EMASK, i10 = pk0 >> 19;
            float we0 = ew[e0]; int s0 = src[e0];
            int e1i = pk1 & EMASK, i11 = pk1 >> 19;
            float we1 = 0.f; int s1 = 0;
            if (j2 < e1) { we1 = ew[e1i]; s1 = src[e1i]; }
            float wt0 = we0 * rsqrtf(fmaxf((float)outcnt[s0], 1.f));
            atomicAdd(&agg1c[(size_t)i10 * F0 + lane],
                      feat[(size_t)s0 * F0 + lane] * wt0);
            if (j2 < e1) {
                float wt1 = we1 * rsqrtf(fmaxf((float)outcnt[s1], 1.f));
                atomicAdd(&agg1c[(size_t)i11 * F0 + lane],
                          feat[(size_t)s1 * F0 + lane] * wt1);
            }
        }
    }
    gbar(bar, 4);

    // ---- phase G': agg2 with h1 computed on the fly (wave per edge) ----
    {
        unsigned e2 = cnts[3]; if (e2 > E2CAP) e2 = E2CAP;
        unsigned w = (unsigned)gid >> 6;
        const unsigned nw = (NBLK * NTHR) >> 6;
        for (unsigned i = w; i < e2; i += nw) {
            unsigned pk = list2[i];
            int e = pk & EMASK, i2 = pk >> 19;
            float we = ew[e]; int s = src[e];
            int i1 = idx1[s]; if (i1 < 0) continue;
            float wt = we * rsqrtf(fmaxf((float)outcnt[s], 1.f));
            float innorm1 = rsqrtf(fmaxf((float)incnt[s], 1.f));
            float rv = agg1c[(size_t)i1 * F0 + lane];
            float acc0 = 0.f, acc1 = 0.f;
            #pragma unroll 8
            for (int k2 = 0; k2 < F0; k2++) {
                float bv = __shfl(rv, k2, 64);
                acc0 += bv * W1[k2 * F1 + lane];
                acc1 += bv * W1[k2 * F1 + lane + 64];
            }
            float h0 = fmaxf(acc0 * innorm1 + b1[lane], 0.f) * wt;
            float h1v = fmaxf(acc1 * innorm1 + b1[lane + 64], 0.f) * wt;
            atomicAdd(&agg2c[(size_t)i2 * F1 + lane], h0);
            atomicAdd(&agg2c[(size_t)i2 * F1 + lane + 64], h1v);
        }
    }
    gbar(bar, 5);

    // ---- phase I': out += (h2-on-the-fly . W3) per e3-edge (wave per edge) ----
    {
        unsigned e3 = cnts[4]; if (e3 > E3CAP) e3 = E3CAP;
        unsigned w = (unsigned)gid >> 6;
        const unsigned nw = (NBLK * NTHR) >> 6;
        for (unsigned i = w; i < e3; i += nw) {
            unsigned pk = list3[i];
            int e = pk & EMASK, g = pk >> 19;
            float we = ew[e]; int s = src[e];
            int i2 = idx2[s]; if (i2 < 0) continue;
            float wt = we * rsqrtf(fmaxf((float)outcnt[s], 1.f))
                          * rsqrtf(fmaxf((float)incnt[tg[g]], 1.f));
            float innorm2 = rsqrtf(fmaxf((float)incnt[s], 1.f));
            float rv0 = agg2c[(size_t)i2 * F1 + lane];
            float rv1 = agg2c[(size_t)i2 * F1 + lane + 64];
            float acc0 = 0.f, acc1 = 0.f;
            #pragma unroll 8
            for (int k2 = 0; k2 < 64; k2++) {
                float bv = __shfl(rv0, k2, 64);
                acc0 += bv * W2[k2 * F1 + lane];
                acc1 += bv * W2[k2 * F1 + lane + 64];
            }
            #pragma unroll 8
            for (int k2 = 0; k2 < 64; k2++) {
                float bv = __shfl(rv1, k2, 64);
                acc0 += bv * W2[(k2 + 64) * F1 + lane];
                acc1 += bv * W2[(k2 + 64) * F1 + lane + 64];
            }
            float h20 = fmaxf(acc0 * innorm2 + b2[lane], 0.f);
            float h21 = fmaxf(acc1 * innorm2 + b2[lane + 64], 0.f);
            float oc0 = (h20 * W3[lane * NCLS + 0] + h21 * W3[(lane + 64) * NCLS + 0]) * wt;
            float oc1 = (h20 * W3[lane * NCLS + 1] + h21 * W3[(lane + 64) * NCLS + 1]) * wt;
            float oc2 = (h20 * W3[lane * NCLS + 2] + h21 * W3[(lane + 64) * NCLS + 2]) * wt;
            float oc3 = (h20 * W3[lane * NCLS + 3] + h21 * W3[(lane + 64) * NCLS + 3]) * wt;
            #pragma unroll
            for (int off = 32; off; off >>= 1) {
                oc0 += __shfl_down(oc0, off, 64);
                oc1 += __shfl_down(oc1, off, 64);
                oc2 += __shfl_down(oc2, off, 64);
                oc3 += __shfl_down(oc3, off, 64);
            }
            if (lane == 0) {
                atomicAdd(&out[g * NCLS + 0], oc0);
                atomicAdd(&out[g * NCLS + 1], oc1);
                atomicAdd(&out[g * NCLS + 2], oc2);
                atomicAdd(&out[g * NCLS + 3], oc3);
            }
        }
    }
}

extern "C" void kernel_launch(void* const* d_in, const int* in_sizes, int n_in,
                              void* d_out, int out_size, void* d_ws, size_t ws_size,
                              hipStream_t stream) {
    const float* in_feat = (const float*)d_in[0];
    const float* ew      = (const float*)d_in[1];
    const int*   src     = (const int*)d_in[2];
    const int*   dst     = (const int*)d_in[3];
    const unsigned* bnn  = (const unsigned*)d_in[4];
    const int*   tnode   = (const int*)d_in[5];
    const float* W1 = (const float*)d_in[6];
    const float* b1 = (const float*)d_in[7];
    const float* W2 = (const float*)d_in[8];
    const float* b2 = (const float*)d_in[9];
    const float* W3 = (const float*)d_in[10];
    const float* b3 = (const float*)d_in[11];
    float* out = (float*)d_out;
    (void)in_sizes; (void)n_in; (void)out_size; (void)ws_size;

    char* ws = (char*)d_ws;
    size_t o = 0;
    auto alloc = [&](size_t bytes) { size_t r = o; o += (bytes + 255) & ~(size_t)255; return r; };

    // --- zero-init region (starts at 0; ~0.45 MB) ---
    size_t off_outcnt = alloc((size_t)NND * 4);
    size_t off_incnt  = alloc((size_t)NND * 4);
    size_t off_cnts   = alloc(8 * 4);
    size_t off_bar    = alloc((size_t)NBAR * (NSUB + 1) * 32 * 4);
    size_t off_bm1    = alloc((size_t)BMW * 4);
    size_t off_bm2    = alloc((size_t)BMW * 4);
    size_t off_bmN    = alloc((size_t)BMW * 4);
    size_t zero_bytes = o;
    // --- 0xFF-init region (0.4 MB) ---
    size_t ff_start = o;
    size_t off_idx2   = alloc((size_t)NND * 4);
    size_t off_idx1   = alloc((size_t)NND * 4);
    size_t ff_bytes = o - ff_start;
    // --- write-before-read region (agg buffers lazily zeroed at claim time) ---
    size_t off_agg1   = alloc((size_t)N1CAP * F0 * 4);
    size_t off_agg2   = alloc((size_t)N2CAP * F1 * 4);
    size_t off_list3  = alloc((size_t)E3CAP * 4);
    size_t off_list2  = alloc((size_t)E2CAP * 4);
    size_t off_list1  = alloc((size_t)E1CAP * 4);

    unsigned* outcnt  = (unsigned*)(ws + off_outcnt);
    unsigned* incnt   = (unsigned*)(ws + off_incnt);
    unsigned* cnts    = (unsigned*)(ws + off_cnts);
    unsigned* bar     = (unsigned*)(ws + off_bar);
    unsigned* bm1     = (unsigned*)(ws + off_bm1);
    unsigned* bm2     = (unsigned*)(ws + off_bm2);
    unsigned* bmN     = (unsigned*)(ws + off_bmN);
    float*    agg1c   = (float*)(ws + off_agg1);
    float*    agg2c   = (float*)(ws + off_agg2);
    int*      idx2    = (int*)(ws + off_idx2);
    int*      idx1    = (int*)(ws + off_idx1);
    unsigned* list3   = (unsigned*)(ws + off_list3);
    unsigned* list2   = (unsigned*)(ws + off_list2);
    unsigned* list1   = (unsigned*)(ws + off_list1);

    unsigned zw = (unsigned)(zero_bytes / 16);
    unsigned fw = (unsigned)(ff_bytes / 16);
    unsigned iw = zw > fw ? zw : fw;
    k_init<<<(int)((iw + 255) / 256), 256, 0, stream>>>(ws, zw, (unsigned)ff_start, fw);

    k_main<<<NBLK, NTHR, 0, stream>>>(in_feat, ew, src, dst, tnode, bnn,
                                      W1, b1, W2, b2, W3, b3, out,
                                      idx1, idx2, list1, list2, list3,
                                      cnts, incnt, outcnt, bm1, bm2, bmN,
                                      agg1c, agg2c, bar);
}

// Round 16
// 62.519 us; speedup vs baseline: 1.3775x; 1.0192x over previous
//
#include <hip/hip_runtime.h>

#define NND 50000
#define NED 500000
#define F0 64
#define F1 128
#define NCLS 4
#define NG 8

#define NBLK 256
#define NTHR 1024
#define EPT 2           // NBLK*NTHR*EPT = 524288 >= NED
#define NBAR 8
#define NSUB 8
#define STG 2048        // per-block edge-hit staging (= NTHR*EPT worst case)
#define STGN 2048
#define BMW ((NND + 31) / 32)
#define EMASK 0x7FFFFu  // e < 2^19 (NED=500000 < 524288)

// capacities (expected: n2~80, e3~80, e2~800, n1~800, e1~8000)
#define N1CAP 4096
#define N2CAP 1024
#define E1CAP 32768
#define E2CAP 8192
#define E3CAP 2048

// cnts: [0]=n1 [1]=n2 [2]=e1 [3]=e2 [4]=e3

// write-through store: lands at the coherence point; safe because no XCD
// normal-reads a line before its FINAL write (audited per buffer), and
// kernel-boundary flushes cover everything else.
template <typename T>
__device__ __forceinline__ void st_wt(T* p, T v) {
    __hip_atomic_store(p, v, __ATOMIC_RELAXED, __HIP_MEMORY_SCOPE_AGENT);
}

__device__ __forceinline__ bool bt(const unsigned* __restrict__ bm, int n) {
    return (bm[n >> 5] >> (n & 31)) & 1u;
}
__device__ __forceinline__ void bset(unsigned* bm, int n) {
    atomicOr(&bm[n >> 5], 1u << (n & 31));
}

__device__ __forceinline__ void load_targets(const int* __restrict__ tnode,
                                             const unsigned* __restrict__ bnn,
                                             int* t) {
    bool is64 = true;
    #pragma unroll
    for (int k = 0; k < 4; k++) if (bnn[2 * k + 1] != 0u) { is64 = false; break; }
    long long off = 0;
    #pragma unroll
    for (int g = 0; g < NG; g++) {
        t[g] = tnode[g] + (int)off;
        off += is64 ? (long long)bnn[2 * g] : (long long)(int)bnn[g];
    }
}

__device__ __forceinline__ int tgt_of(int d, const int* t) {
    int g = -1;
    #pragma unroll
    for (int k = 0; k < NG; k++) if (d == t[k]) g = k;
    return g;
}

// Fence-free grid barrier (R7/R8-proven): write-through data + vmcnt drain
// before s_barrier; two-level arrival; relaxed-load poll.
__device__ __forceinline__ void gbar(unsigned* bar, int i) {
    asm volatile("s_waitcnt vmcnt(0)" ::: "memory");
    __syncthreads();
    if (threadIdx.x == 0) {
        unsigned* sp = bar + (size_t)(i * (NSUB + 1) + (blockIdx.x & (NSUB - 1))) * 32;
        unsigned* mp = bar + (size_t)(i * (NSUB + 1) + NSUB) * 32;
        unsigned old = __hip_atomic_fetch_add(sp, 1u, __ATOMIC_RELAXED,
                                              __HIP_MEMORY_SCOPE_AGENT);
        if (old + 1u == (unsigned)(NBLK / NSUB))
            __hip_atomic_fetch_add(mp, 1u, __ATOMIC_RELAXED, __HIP_MEMORY_SCOPE_AGENT);
        while (__hip_atomic_load(mp, __ATOMIC_RELAXED, __HIP_MEMORY_SCOPE_AGENT)
               < (unsigned)NSUB)
            __builtin_amdgcn_s_sleep(1);
    }
    __syncthreads();
}

// workspace init: zero region + 0xFF region, 16B stores
__global__ __launch_bounds__(256) void k_init(char* ws, unsigned zw, unsigned foff, unsigned fw) {
    unsigned t = blockIdx.x * blockDim.x + threadIdx.x;
    if (t < zw) ((uint4*)ws)[t] = make_uint4(0u, 0u, 0u, 0u);
    if (t < fw) ((uint4*)(ws + foff))[t] = make_uint4(~0u, ~0u, ~0u, ~0u);
}

__global__ __launch_bounds__(NTHR) void k_main(
        const float* __restrict__ feat, const float* __restrict__ ew,
        const int* __restrict__ src, const int* __restrict__ dst,
        const int* __restrict__ tnode, const unsigned* __restrict__ bnn,
        const float* __restrict__ W1, const float* __restrict__ b1,
        const float* __restrict__ W2, const float* __restrict__ b2,
        const float* __restrict__ W3, const float* __restrict__ b3,
        float* out,
        int* idx1, int* idx2,
        unsigned* list1, unsigned* list2, unsigned* list3,
        unsigned* cnts, unsigned* incnt, unsigned* outcnt,
        unsigned* bm1, unsigned* bm2, unsigned* bmN,
        float* agg1c, float* agg2c, unsigned* bar) {
    __shared__ unsigned s_le, s_ln, s_eb, s_nb;
    __shared__ unsigned stage[STG];
    __shared__ int stageN[STGN];

    const int tid = threadIdx.x;
    const int gid = blockIdx.x * NTHR + tid;
    const int lane = tid & 63;
    int tg[NG]; load_targets(tnode, bnn, tg);

    // ---- phase A: edges into targets -> list3 {g|e}; claim node2; tgt in-deg ----
    {
        if (tid == 0) { s_le = 0; s_ln = 0; }
        __syncthreads();
        int base = gid * EPT;
        if (base < NED) {
            int2 d2 = *(const int2*)(dst + base);
            int dd[2] = {d2.x, d2.y};
            #pragma unroll
            for (int k = 0; k < 2; k++) {
                int d = dd[k];
                int g = tgt_of(d, tg);
                if (g >= 0) {
                    int e = base + k;
                    stage[atomicAdd(&s_le, 1u)] = ((unsigned)g << 19) | (unsigned)e;
                    atomicAdd(&incnt[d], 1u);
                    int s = src[e];
                    bset(bmN, s);
                    if (atomicCAS(&idx2[s], -1, -2) == -1) {
                        bset(bm2, s);
                        stageN[atomicAdd(&s_ln, 1u)] = s;
                    }
                }
            }
        }
        __syncthreads();
        if (tid == 0) {
            s_eb = s_le ? atomicAdd(&cnts[4], s_le) : 0u;
            s_nb = s_ln ? atomicAdd(&cnts[1], s_ln) : 0u;
        }
        __syncthreads();
        for (unsigned t = tid; t < s_le; t += NTHR) {
            unsigned p = s_eb + t; if (p < E3CAP) st_wt(&list3[p], stage[t]);
        }
        for (unsigned t = tid; t < s_ln; t += NTHR) {
            int s = stageN[t]; unsigned id = s_nb + t;
            st_wt(&idx2[s], id < N2CAP ? (int)id : -1);
        }
        if (blockIdx.x == 0 && tid < NG * NCLS) st_wt(&out[tid], b3[tid & 3]);
    }
    gbar(bar, 0);

    // ---- phase B: edges into node2 -> list2 {i2|e}; claim node1 ----
    {
        if (tid == 0) { s_le = 0; s_ln = 0; }
        __syncthreads();
        int base = gid * EPT;
        if (base < NED) {
            int2 d2 = *(const int2*)(dst + base);
            int dd[2] = {d2.x, d2.y};
            #pragma unroll
            for (int k = 0; k < 2; k++) {
                int d = dd[k];
                if (bt(bm2, d)) {
                    int iv = idx2[d];
                    if (iv >= 0) {
                        int e = base + k;
                        stage[atomicAdd(&s_le, 1u)] = ((unsigned)iv << 19) | (unsigned)e;
                        if (tgt_of(d, tg) < 0) atomicAdd(&incnt[d], 1u);
                        int s = src[e];
                        bset(bmN, s);
                        if (atomicCAS(&idx1[s], -1, -2) == -1) {
                            bset(bm1, s);
                            stageN[atomicAdd(&s_ln, 1u)] = s;
                        }
                    }
                }
            }
        }
        __syncthreads();
        if (tid == 0) {
            s_eb = s_le ? atomicAdd(&cnts[3], s_le) : 0u;
            s_nb = s_ln ? atomicAdd(&cnts[0], s_ln) : 0u;
        }
        __syncthreads();
        for (unsigned t = tid; t < s_le; t += NTHR) {
            unsigned p = s_eb + t; if (p < E2CAP) st_wt(&list2[p], stage[t]);
        }
        for (unsigned t = tid; t < s_ln; t += NTHR) {
            int s = stageN[t]; unsigned id = s_nb + t;
            st_wt(&idx1[s], id < N1CAP ? (int)id : -1);
        }
    }
    gbar(bar, 1);

    // ---- phase C: edges into node1 -> list1 {i1|e}; node1-only in-deg ----
    {
        if (tid == 0) s_le = 0;
        __syncthreads();
        int base = gid * EPT;
        if (base < NED) {
            int2 d2 = *(const int2*)(dst + base);
            int dd[2] = {d2.x, d2.y};
            #pragma unroll
            for (int k = 0; k < 2; k++) {
                int d = dd[k];
                if (bt(bm1, d)) {
                    int iv = idx1[d];
                    if (iv >= 0) {
                        int e = base + k;
                        stage[atomicAdd(&s_le, 1u)] = ((unsigned)iv << 19) | (unsigned)e;
                        if (idx2[d] < 0 && tgt_of(d, tg) < 0) atomicAdd(&incnt[d], 1u);
                        bset(bmN, src[e]);
                    }
                }
            }
        }
        __syncthreads();
        if (tid == 0) s_eb = s_le ? atomicAdd(&cnts[2], s_le) : 0u;
        __syncthreads();
        for (unsigned t = tid; t < s_le; t += NTHR) {
            unsigned p = s_eb + t; if (p < E1CAP) st_wt(&list1[p], stage[t]);
        }
    }
    gbar(bar, 2);

    // ---- phase D: filtered out-degree (bmN test) ----
    {
        int base = gid * EPT;
        if (base < NED) {
            int2 s2 = *(const int2*)(src + base);
            int ss[2] = {s2.x, s2.y};
            #pragma unroll
            for (int k = 0; k < 2; k++)
                if (bt(bmN, ss[k])) atomicAdd(&outcnt[ss[k]], 1u);
        }
    }
    gbar(bar, 3);

    // ---- phase E: agg1 (wave per edge, packed list, 2-way ILP) ----
    {
        unsigned e1 = cnts[2]; if (e1 > E1CAP) e1 = E1CAP;
        unsigned w = (unsigned)gid >> 6;
        const unsigned nw = (NBLK * NTHR) >> 6;
        for (unsigned i = w; i < e1; i += 2 * nw) {
            unsigned pk0 = list1[i];
            unsigned j2 = i + nw;
            unsigned pk1 = (j2 < e1) ? list1[j2] : 0u;
            int e0 = pk0 & EMASK, i10 = pk0 >> 19;
            float we0 = ew[e0]; int s0 = src[e0];
            int e1i = pk1 & EMASK, i11 = pk1 >> 19;
            float we1 = 0.f; int s1 = 0;
            if (j2 < e1) { we1 = ew[e1i]; s1 = src[e1i]; }
            float wt0 = we0 * rsqrtf(fmaxf((float)outcnt[s0], 1.f));
            atomicAdd(&agg1c[(size_t)i10 * F0 + lane],
                      feat[(size_t)s0 * F0 + lane] * wt0);
            if (j2 < e1) {
                float wt1 = we1 * rsqrtf(fmaxf((float)outcnt[s1], 1.f));
                atomicAdd(&agg1c[(size_t)i11 * F0 + lane],
                          feat[(size_t)s1 * F0 + lane] * wt1);
            }
        }
    }
    gbar(bar, 4);

    // ---- phase G': agg2 with h1 computed on the fly (wave per edge) ----
    {
        unsigned e2 = cnts[3]; if (e2 > E2CAP) e2 = E2CAP;
        unsigned w = (unsigned)gid >> 6;
        const unsigned nw = (NBLK * NTHR) >> 6;
        for (unsigned i = w; i < e2; i += nw) {
            unsigned pk = list2[i];
            int e = pk & EMASK, i2 = pk >> 19;
            float we = ew[e]; int s = src[e];
            int i1 = idx1[s]; if (i1 < 0) continue;
            float wt = we * rsqrtf(fmaxf((float)outcnt[s], 1.f));
            float innorm1 = rsqrtf(fmaxf((float)incnt[s], 1.f));
            float rv = agg1c[(size_t)i1 * F0 + lane];
            float acc0 = 0.f, acc1 = 0.f;
            #pragma unroll 8
            for (int k2 = 0; k2 < F0; k2++) {
                float bv = __shfl(rv, k2, 64);
                acc0 += bv * W1[k2 * F1 + lane];
                acc1 += bv * W1[k2 * F1 + lane + 64];
            }
            float h0 = fmaxf(acc0 * innorm1 + b1[lane], 0.f) * wt;
            float h1v = fmaxf(acc1 * innorm1 + b1[lane + 64], 0.f) * wt;
            atomicAdd(&agg2c[(size_t)i2 * F1 + lane], h0);
            atomicAdd(&agg2c[(size_t)i2 * F1 + lane + 64], h1v);
        }
    }
    gbar(bar, 5);

    // ---- phase I': out += (h2-on-the-fly . W3) per e3-edge (wave per edge) ----
    {
        unsigned e3 = cnts[4]; if (e3 > E3CAP) e3 = E3CAP;
        unsigned w = (unsigned)gid >> 6;
        const unsigned nw = (NBLK * NTHR) >> 6;
        for (unsigned i = w; i < e3; i += nw) {
            unsigned pk = list3[i];
            int e = pk & EMASK, g = pk >> 19;
            float we = ew[e]; int s = src[e];
            int i2 = idx2[s]; if (i2 < 0) continue;
            float wt = we * rsqrtf(fmaxf((float)outcnt[s], 1.f))
                          * rsqrtf(fmaxf((float)incnt[tg[g]], 1.f));
            float innorm2 = rsqrtf(fmaxf((float)incnt[s], 1.f));
            float rv0 = agg2c[(size_t)i2 * F1 + lane];
            float rv1 = agg2c[(size_t)i2 * F1 + lane + 64];
            float acc0 = 0.f, acc1 = 0.f;
            #pragma unroll 8
            for (int k2 = 0; k2 < 64; k2++) {
                float bv = __shfl(rv0, k2, 64);
                acc0 += bv * W2[k2 * F1 + lane];
                acc1 += bv * W2[k2 * F1 + lane + 64];
            }
            #pragma unroll 8
            for (int k2 = 0; k2 < 64; k2++) {
                float bv = __shfl(rv1, k2, 64);
                acc0 += bv * W2[(k2 + 64) * F1 + lane];
                acc1 += bv * W2[(k2 + 64) * F1 + lane + 64];
            }
            float h20 = fmaxf(acc0 * innorm2 + b2[lane], 0.f);
            float h21 = fmaxf(acc1 * innorm2 + b2[lane + 64], 0.f);
            float oc0 = (h20 * W3[lane * NCLS + 0] + h21 * W3[(lane + 64) * NCLS + 0]) * wt;
            float oc1 = (h20 * W3[lane * NCLS + 1] + h21 * W3[(lane + 64) * NCLS + 1]) * wt;
            float oc2 = (h20 * W3[lane * NCLS + 2] + h21 * W3[(lane + 64) * NCLS + 2]) * wt;
            float oc3 = (h20 * W3[lane * NCLS + 3] + h21 * W3[(lane + 64) * NCLS + 3]) * wt;
            #pragma unroll
            for (int off = 32; off; off >>= 1) {
                oc0 += __shfl_down(oc0, off, 64);
                oc1 += __shfl_down(oc1, off, 64);
                oc2 += __shfl_down(oc2, off, 64);
                oc3 += __shfl_down(oc3, off, 64);
            }
            if (lane == 0) {
                atomicAdd(&out[g * NCLS + 0], oc0);
                atomicAdd(&out[g * NCLS + 1], oc1);
                atomicAdd(&out[g * NCLS + 2], oc2);
                atomicAdd(&out[g * NCLS + 3], oc3);
            }
        }
    }
}

extern "C" void kernel_launch(void* const* d_in, const int* in_sizes, int n_in,
                              void* d_out, int out_size, void* d_ws, size_t ws_size,
                              hipStream_t stream) {
    const float* in_feat = (const float*)d_in[0];
    const float* ew      = (const float*)d_in[1];
    const int*   src     = (const int*)d_in[2];
    const int*   dst     = (const int*)d_in[3];
    const unsigned* bnn  = (const unsigned*)d_in[4];
    const int*   tnode   = (const int*)d_in[5];
    const float* W1 = (const float*)d_in[6];
    const float* b1 = (const float*)d_in[7];
    const float* W2 = (const float*)d_in[8];
    const float* b2 = (const float*)d_in[9];
    const float* W3 = (const float*)d_in[10];
    const float* b3 = (const float*)d_in[11];
    float* out = (float*)d_out;
    (void)in_sizes; (void)n_in; (void)out_size; (void)ws_size;

    char* ws = (char*)d_ws;
    size_t o = 0;
    auto alloc = [&](size_t bytes) { size_t r = o; o += (bytes + 255) & ~(size_t)255; return r; };

    // --- zero-init region (starts at 0) ---
    size_t off_outcnt = alloc((size_t)NND * 4);
    size_t off_incnt  = alloc((size_t)NND * 4);
    size_t off_cnts   = alloc(8 * 4);
    size_t off_bar    = alloc((size_t)NBAR * (NSUB + 1) * 32 * 4);
    size_t off_bm1    = alloc((size_t)BMW * 4);
    size_t off_bm2    = alloc((size_t)BMW * 4);
    size_t off_bmN    = alloc((size_t)BMW * 4);
    size_t off_agg1   = alloc((size_t)N1CAP * F0 * 4);
    size_t off_agg2   = alloc((size_t)N2CAP * F1 * 4);
    size_t zero_bytes = o;
    // --- 0xFF-init region ---
    size_t ff_start = o;
    size_t off_idx2   = alloc((size_t)NND * 4);
    size_t off_idx1   = alloc((size_t)NND * 4);
    size_t ff_bytes = o - ff_start;
    // --- write-before-read region ---
    size_t off_list3   = alloc((size_t)E3CAP * 4);
    size_t off_list2   = alloc((size_t)E2CAP * 4);
    size_t off_list1   = alloc((size_t)E1CAP * 4);

    unsigned* outcnt  = (unsigned*)(ws + off_outcnt);
    unsigned* incnt   = (unsigned*)(ws + off_incnt);
    unsigned* cnts    = (unsigned*)(ws + off_cnts);
    unsigned* bar     = (unsigned*)(ws + off_bar);
    unsigned* bm1     = (unsigned*)(ws + off_bm1);
    unsigned* bm2     = (unsigned*)(ws + off_bm2);
    unsigned* bmN     = (unsigned*)(ws + off_bmN);
    float*    agg1c   = (float*)(ws + off_agg1);
    float*    agg2c   = (float*)(ws + off_agg2);
    int*      idx2    = (int*)(ws + off_idx2);
    int*      idx1    = (int*)(ws + off_idx1);
    unsigned* list3   = (unsigned*)(ws + off_list3);
    unsigned* list2   = (unsigned*)(ws + off_list2);
    unsigned* list1   = (unsigned*)(ws + off_list1);

    unsigned zw = (unsigned)(zero_bytes / 16);
    unsigned fw = (unsigned)(ff_bytes / 16);
    unsigned iw = zw > fw ? zw : fw;
    k_init<<<(int)((iw + 255) / 256), 256, 0, stream>>>(ws, zw, (unsigned)ff_start, fw);

    k_main<<<NBLK, NTHR, 0, stream>>>(in_feat, ew, src, dst, tnode, bnn,
                                      W1, b1, W2, b2, W3, b3, out,
                                      idx1, idx2, list1, list2, list3,
                                      cnts, incnt, outcnt, bm1, bm2, bmN,
                                      agg1c, agg2c, bar);
}